// Round 4
// baseline (365.593 us; speedup 1.0000x reference)
//
#include <hip/hip_runtime.h>

// Problem constants (B=2, S=1024, D=1024, H=16, hd=64, L=4, M=12)
#define BATCH 2
#define SEQ   1024
#define DIM   1024
#define NH    16
#define HD    64
#define NM    12
#define NTOK  (BATCH*SEQ)          // 2048
#define MEMROWS (BATCH*SEQ*NM)     // 24576
#define OUTT  2097152              // elements per output tensor
#define NEGBIG (-1.0e30f)

typedef __attribute__((ext_vector_type(8))) short short8;   // 8 bf16 (4 VGPRs)
typedef __attribute__((ext_vector_type(4))) float f32x4;    // MFMA C/D

__device__ __forceinline__ float bf2f(ushort u) {
    union { unsigned int i; float f; } t; t.i = ((unsigned int)u) << 16; return t.f;
}
__device__ __forceinline__ ushort f2bf(float f) {
    union { float f; unsigned int i; } t; t.f = f;
    unsigned int i = t.i;
    unsigned int lsb = (i >> 16) & 1u;
    i += 0x7fffu + lsb;
    return (ushort)(i >> 16);
}

// ---------------------------------------------------------------------------
// fp32 -> bf16 conversion for x, Wqkv, Wout (one pass, float4-vectorized)
// ---------------------------------------------------------------------------
__global__ __launch_bounds__(256) void cvt3_kernel(
    const float* __restrict__ a, ushort* __restrict__ ab, int na4,
    const float* __restrict__ b, ushort* __restrict__ bb, int nb4,
    const float* __restrict__ c, ushort* __restrict__ cb, int nc4)
{
    int i = blockIdx.x * 256 + threadIdx.x;
    if (i >= na4 + nb4 + nc4) return;
    const float* src; ushort* dst; int j;
    if (i < na4)            { src = a; dst = ab; j = i; }
    else if (i < na4 + nb4) { src = b; dst = bb; j = i - na4; }
    else                    { src = c; dst = cb; j = i - na4 - nb4; }
    float4 v = ((const float4*)src)[j];
    ushort4 o; o.x = f2bf(v.x); o.y = f2bf(v.y); o.z = f2bf(v.z); o.w = f2bf(v.w);
    ((ushort4*)dst)[j] = o;
}

// ---------------------------------------------------------------------------
// MFMA GEMM core conventions (verified):
//  A-frag: m=lane&15, k=qd*8+j ; B-frag: n=lane&15, k=qd*8+j
//  C/D:    col=lane&15, row=qd*4+reg
// LDS tiles padded to 40 elems/row (80 B, 16B-aligned).
// ---------------------------------------------------------------------------

// qkv GEMM: [2048x1024]x[3072x1024]^T + bias -> fp32 k,v,q in d_out + bf16 qkvb
__global__ __launch_bounds__(256) void mfma_qkv_kernel(
    const ushort* __restrict__ xb, const ushort* __restrict__ Wb,
    const float* __restrict__ bias, float* __restrict__ out,
    ushort* __restrict__ qkvb)
{
    __shared__ ushort As[128][40];
    __shared__ ushort Bs[128][40];
    const int tid = threadIdx.x;
    const int w = tid >> 6, lane = tid & 63;
    const int n = lane & 15, qd = lane >> 4;
    const int wr = (w >> 1) * 64, wc = (w & 1) * 64;
    const int row0 = blockIdx.y * 128, col0 = blockIdx.x * 128;
    const int r1 = tid >> 2, o1 = (tid & 3) * 8;
    const int r2 = (tid + 256) >> 2, o2 = ((tid + 256) & 3) * 8;

    f32x4 acc[4][4];
#pragma unroll
    for (int mt = 0; mt < 4; mt++)
#pragma unroll
        for (int nt = 0; nt < 4; nt++) acc[mt][nt] = (f32x4){0.f, 0.f, 0.f, 0.f};

    for (int k0 = 0; k0 < 1024; k0 += 32) {
        *(short8*)&As[r1][o1] = *(const short8*)(xb + (size_t)(row0 + r1) * 1024 + k0 + o1);
        *(short8*)&As[r2][o2] = *(const short8*)(xb + (size_t)(row0 + r2) * 1024 + k0 + o2);
        *(short8*)&Bs[r1][o1] = *(const short8*)(Wb + (size_t)(col0 + r1) * 1024 + k0 + o1);
        *(short8*)&Bs[r2][o2] = *(const short8*)(Wb + (size_t)(col0 + r2) * 1024 + k0 + o2);
        __syncthreads();
        short8 af[4], bf[4];
#pragma unroll
        for (int mt = 0; mt < 4; mt++) af[mt] = *(const short8*)&As[wr + mt * 16 + n][qd * 8];
#pragma unroll
        for (int nt = 0; nt < 4; nt++) bf[nt] = *(const short8*)&Bs[wc + nt * 16 + n][qd * 8];
#pragma unroll
        for (int mt = 0; mt < 4; mt++)
#pragma unroll
            for (int nt = 0; nt < 4; nt++)
                acc[mt][nt] = __builtin_amdgcn_mfma_f32_16x16x32_bf16(af[mt], bf[nt], acc[mt][nt], 0, 0, 0);
        __syncthreads();
    }
#pragma unroll
    for (int mt = 0; mt < 4; mt++)
#pragma unroll
        for (int nt = 0; nt < 4; nt++)
#pragma unroll
            for (int r = 0; r < 4; r++) {
                int row = row0 + wr + mt * 16 + qd * 4 + r;
                int col = col0 + wc + nt * 16 + n;
                float val = acc[mt][nt][r] + bias[col];
                int t = col >> 10, h = (col >> 6) & 15, d = col & 63;
                int b = row >> 10, s = row & 1023;
                size_t idx = (((size_t)(b * NH + h) * SEQ + s) * HD) + d;
                size_t base = (t == 0) ? (size_t)3 * OUTT : (t == 1) ? (size_t)OUTT : (size_t)2 * OUTT;
                out[base + idx] = val;
                qkvb[(size_t)t * OUTT + idx] = f2bf(val);
            }
}

// out GEMM: mergedb[2048x1024] x Woutb[1024x1024]^T + bout -> d_out fp32
__global__ __launch_bounds__(256) void mfma_out_kernel(
    const ushort* __restrict__ Ab, const ushort* __restrict__ Wb,
    const float* __restrict__ bias, float* __restrict__ C)
{
    __shared__ ushort As[128][40];
    __shared__ ushort Bs[128][40];
    const int tid = threadIdx.x;
    const int w = tid >> 6, lane = tid & 63;
    const int n = lane & 15, qd = lane >> 4;
    const int wr = (w >> 1) * 64, wc = (w & 1) * 64;
    const int row0 = blockIdx.y * 128, col0 = blockIdx.x * 128;
    const int r1 = tid >> 2, o1 = (tid & 3) * 8;
    const int r2 = (tid + 256) >> 2, o2 = ((tid + 256) & 3) * 8;

    f32x4 acc[4][4];
#pragma unroll
    for (int mt = 0; mt < 4; mt++)
#pragma unroll
        for (int nt = 0; nt < 4; nt++) acc[mt][nt] = (f32x4){0.f, 0.f, 0.f, 0.f};

    for (int k0 = 0; k0 < 1024; k0 += 32) {
        *(short8*)&As[r1][o1] = *(const short8*)(Ab + (size_t)(row0 + r1) * 1024 + k0 + o1);
        *(short8*)&As[r2][o2] = *(const short8*)(Ab + (size_t)(row0 + r2) * 1024 + k0 + o2);
        *(short8*)&Bs[r1][o1] = *(const short8*)(Wb + (size_t)(col0 + r1) * 1024 + k0 + o1);
        *(short8*)&Bs[r2][o2] = *(const short8*)(Wb + (size_t)(col0 + r2) * 1024 + k0 + o2);
        __syncthreads();
        short8 af[4], bf[4];
#pragma unroll
        for (int mt = 0; mt < 4; mt++) af[mt] = *(const short8*)&As[wr + mt * 16 + n][qd * 8];
#pragma unroll
        for (int nt = 0; nt < 4; nt++) bf[nt] = *(const short8*)&Bs[wc + nt * 16 + n][qd * 8];
#pragma unroll
        for (int mt = 0; mt < 4; mt++)
#pragma unroll
            for (int nt = 0; nt < 4; nt++)
                acc[mt][nt] = __builtin_amdgcn_mfma_f32_16x16x32_bf16(af[mt], bf[nt], acc[mt][nt], 0, 0, 0);
        __syncthreads();
    }
#pragma unroll
    for (int mt = 0; mt < 4; mt++)
#pragma unroll
        for (int nt = 0; nt < 4; nt++)
#pragma unroll
            for (int r = 0; r < 4; r++) {
                int row = row0 + wr + mt * 16 + qd * 4 + r;
                int col = col0 + wc + nt * 16 + n;
                C[(size_t)row * 1024 + col] = acc[mt][nt][r] + bias[col];
            }
}

// qproj per head: q_h[2048x64] @ WkBlock_h[64x1024] -> qproj bf16 (B transposed on stage)
__global__ __launch_bounds__(256) void mfma_qproj_kernel(
    const ushort* __restrict__ qkvb, const ushort* __restrict__ Wkb,
    ushort* __restrict__ qproj)
{
    __shared__ ushort As[128][40];
    __shared__ ushort Bs[128][40];
    const int tid = threadIdx.x;
    const int w = tid >> 6, lane = tid & 63;
    const int n = lane & 15, qd = lane >> 4;
    const int wr = (w >> 1) * 64, wc = (w & 1) * 64;
    const int row0 = blockIdx.y * 128, col0 = blockIdx.x * 128;
    const int h = blockIdx.z;
    const int b = row0 >> 10, s0 = row0 & 1023;
    const ushort* Abase = qkvb + ((size_t)(b * NH + h) * SEQ + s0) * HD;
    const int r1 = tid >> 2, o1 = (tid & 3) * 8;
    const int r2 = (tid + 256) >> 2, o2 = ((tid + 256) & 3) * 8;
    const int bkk = tid >> 3, bc0 = (tid & 7) * 16;

    f32x4 acc[4][4];
#pragma unroll
    for (int mt = 0; mt < 4; mt++)
#pragma unroll
        for (int nt = 0; nt < 4; nt++) acc[mt][nt] = (f32x4){0.f, 0.f, 0.f, 0.f};

    for (int k0 = 0; k0 < 64; k0 += 32) {
        *(short8*)&As[r1][o1] = *(const short8*)(Abase + (size_t)r1 * HD + k0 + o1);
        *(short8*)&As[r2][o2] = *(const short8*)(Abase + (size_t)r2 * HD + k0 + o2);
        // B transpose stage: Bs[c][kk] = Wk[h*64+k0+kk][col0+c]
        {
            const ushort* bsrc = Wkb + (size_t)(h * HD + k0 + bkk) * 1024 + col0 + bc0;
            ushort tmp[16];
            *(short8*)&tmp[0] = *(const short8*)bsrc;
            *(short8*)&tmp[8] = *(const short8*)(bsrc + 8);
#pragma unroll
            for (int i = 0; i < 16; i++) Bs[bc0 + i][bkk] = tmp[i];
        }
        __syncthreads();
        short8 af[4], bf[4];
#pragma unroll
        for (int mt = 0; mt < 4; mt++) af[mt] = *(const short8*)&As[wr + mt * 16 + n][qd * 8];
#pragma unroll
        for (int nt = 0; nt < 4; nt++) bf[nt] = *(const short8*)&Bs[wc + nt * 16 + n][qd * 8];
#pragma unroll
        for (int mt = 0; mt < 4; mt++)
#pragma unroll
            for (int nt = 0; nt < 4; nt++)
                acc[mt][nt] = __builtin_amdgcn_mfma_f32_16x16x32_bf16(af[mt], bf[nt], acc[mt][nt], 0, 0, 0);
        __syncthreads();
    }
#pragma unroll
    for (int mt = 0; mt < 4; mt++)
#pragma unroll
        for (int nt = 0; nt < 4; nt++)
#pragma unroll
            for (int r = 0; r < 4; r++) {
                int token = row0 + wr + mt * 16 + qd * 4 + r;
                int col = col0 + wc + nt * 16 + n;
                qproj[((size_t)token * NH + h) * 1024 + col] = f2bf(acc[mt][nt][r]);
            }
}

// vproj per head: merged[t, h*64+d] += wvec_h[t,:]·Wv[h*64+d,:] + wsum*bv (in-place bf16)
__global__ __launch_bounds__(256) void mfma_vproj_kernel(
    const ushort* __restrict__ wvecb, const ushort* __restrict__ Wvb,
    const float* __restrict__ bv, const float* __restrict__ wmem,
    ushort* __restrict__ mergedb)
{
    __shared__ ushort As[128][40];
    __shared__ ushort Bs[64][40];
    const int tid = threadIdx.x;
    const int w = tid >> 6, lane = tid & 63;
    const int n = lane & 15, qd = lane >> 4;
    const int wr = (w >> 1) * 64, wc = (w & 1) * 32;
    const int row0 = blockIdx.x * 128;
    const int h = blockIdx.y;
    const int r1 = tid >> 2, o1 = (tid & 3) * 8;
    const int r2 = (tid + 256) >> 2, o2 = ((tid + 256) & 3) * 8;

    f32x4 acc[4][2];
#pragma unroll
    for (int mt = 0; mt < 4; mt++)
#pragma unroll
        for (int nt = 0; nt < 2; nt++) acc[mt][nt] = (f32x4){0.f, 0.f, 0.f, 0.f};

    for (int k0 = 0; k0 < 1024; k0 += 32) {
        *(short8*)&As[r1][o1] = *(const short8*)(wvecb + ((size_t)(row0 + r1) * NH + h) * 1024 + k0 + o1);
        *(short8*)&As[r2][o2] = *(const short8*)(wvecb + ((size_t)(row0 + r2) * NH + h) * 1024 + k0 + o2);
        *(short8*)&Bs[r1 & 63][o1] = *(const short8*)(Wvb + (size_t)(h * HD + (r1 & 63)) * 1024 + k0 + o1);
        __syncthreads();
        short8 af[4], bf[2];
#pragma unroll
        for (int mt = 0; mt < 4; mt++) af[mt] = *(const short8*)&As[wr + mt * 16 + n][qd * 8];
#pragma unroll
        for (int nt = 0; nt < 2; nt++) bf[nt] = *(const short8*)&Bs[wc + nt * 16 + n][qd * 8];
#pragma unroll
        for (int mt = 0; mt < 4; mt++)
#pragma unroll
            for (int nt = 0; nt < 2; nt++)
                acc[mt][nt] = __builtin_amdgcn_mfma_f32_16x16x32_bf16(af[mt], bf[nt], acc[mt][nt], 0, 0, 0);
        __syncthreads();
    }
#pragma unroll
    for (int mt = 0; mt < 4; mt++)
#pragma unroll
        for (int nt = 0; nt < 2; nt++)
#pragma unroll
            for (int r = 0; r < 4; r++) {
                int token = row0 + wr + mt * 16 + qd * 4 + r;
                int d = wc + nt * 16 + n;
                float ws = wmem[((size_t)token * NH + h) * 16 + 12];
                size_t mi = (size_t)token * DIM + h * HD + d;
                float val = bf2f(mergedb[mi]) + acc[mt][nt][r] + ws * bv[h * HD + d];
                mergedb[mi] = f2bf(val);
            }
}

// mem_scores fused: per token, D[h][m] = qproj_h · mem_m via one MFMA chain.
__global__ __launch_bounds__(256) void msc_fused_kernel(
    const ushort* __restrict__ qproj, const ushort* __restrict__ mem_n,
    const ushort* __restrict__ qkvb, const float* __restrict__ bqkv,
    float* __restrict__ msc)
{
    const int tid = threadIdx.x;
    const int w = tid >> 6, lane = tid & 63;
    const int n = lane & 15, qd = lane >> 4;
    const int bs = blockIdx.x * 4 + w;

    float qbk = 0.f;
    if (lane < 16) {
        int b = bs >> 10, s = bs & 1023;
        const ushort* qrow = qkvb + ((size_t)(b * NH + lane) * SEQ + s) * HD;
        const float* bk = bqkv + DIM + lane * HD;
#pragma unroll
        for (int d = 0; d < HD; d++) qbk += bf2f(qrow[d]) * bk[d];
    }
    f32x4 acc = (f32x4){0.f, 0.f, 0.f, 0.f};
    const ushort* qpB = qproj + ((size_t)bs * NH + n) * 1024;
    const int mrow = (n < NM) ? n : 0;
    const ushort* mmB = mem_n + ((size_t)bs * NM + mrow) * 1024;
    for (int k0 = 0; k0 < 1024; k0 += 32) {
        short8 af = *(const short8*)(qpB + k0 + qd * 8);
        short8 bf = *(const short8*)(mmB + k0 + qd * 8);
        acc = __builtin_amdgcn_mfma_f32_16x16x32_bf16(af, bf, acc, 0, 0, 0);
    }
#pragma unroll
    for (int r = 0; r < 4; r++) {
        int h = qd * 4 + r;
        float qb = __shfl(qbk, h);
        if (n < NM)
            msc[((size_t)bs * NH + h) * NM + n] = 0.125f * (acc[r] + qb);
    }
}

// ---------------------------------------------------------------------------
// LayerNorm of mem rows (fp32 in, bf16 out) — CONTIGUOUS-READ version.
// Block = (src, layer, batch, 16-s chunk). Reads each of the 16 head planes
// as a contiguous 4KB sweep (1 float4/thread/plane), stashes fp32 in a
// 64KB LDS tile [16 s][1024 c], per-s stats via register accum + 16-lane
// shfl_xor reduce (1 barrier). Phase 2 normalizes and writes each output
// row as 2KB contiguous ushort4 stores.
// Theory: prior versions' 256B-granule strided reads pinned HBM at 2.1 TB/s;
// sequential sweeps should restore streaming BW.
// ---------------------------------------------------------------------------
__global__ __launch_bounds__(256) void ln_mem_kernel(
    const float* __restrict__ pq, const float* __restrict__ pk,
    const float* __restrict__ pv, ushort* __restrict__ mem_n)
{
    __shared__ float tile[16][1024];   // 64 KB
    __shared__ float smu[16], sinv[16];

    const int bid = blockIdx.x;        // 0..1535
    const int chunk = bid & 63;        // 16-s chunk within SEQ
    const int b = (bid >> 6) & 1;
    const int l = (bid >> 7) & 3;
    const int c = bid >> 9;            // 0=q 1=k 2=v
    const float* src = (c == 0) ? pq : ((c == 1) ? pk : pv);
    const size_t pbase = (size_t)((l * BATCH + b) * NH) * (SEQ * HD);
    const int s0 = chunk * 16;
    const int tid = threadIdx.x;
    const int sl = tid >> 4;           // s-local 0..15 (this thread's s-row)
    const int dq = (tid & 15) * 4;     // d-offset 0..60

    float sum = 0.f, sq = 0.f;
#pragma unroll
    for (int h = 0; h < 16; h++) {
        // plane chunk: [s0..s0+15] x [0..63] fp32, contiguous 4KB; thread tid
        // reads float4 at byte offset tid*16 -> fully coalesced.
        float4 v = *(const float4*)(src + pbase + (size_t)h * (SEQ * HD)
                                    + (size_t)(s0 + sl) * HD + dq);
        *(float4*)&tile[sl][h * 64 + dq] = v;
        sum += v.x + v.y + v.z + v.w;
        sq  += v.x * v.x + v.y * v.y + v.z * v.z + v.w * v.w;
    }
    // reduce over the 16 lanes sharing this s-row (within-wave groups)
#pragma unroll
    for (int off = 8; off > 0; off >>= 1) {
        sum += __shfl_xor(sum, off);
        sq  += __shfl_xor(sq, off);
    }
    if ((tid & 15) == 0) {
        float mu  = sum * (1.f / 1024.f);
        float var = fmaxf(sq * (1.f / 1024.f) - mu * mu, 0.f);
        smu[sl]  = mu;
        sinv[sl] = rsqrtf(var + 1e-5f);
    }
    __syncthreads();

    // phase 2: normalize + write. Row r(s) = (b*1024+s)*12 + c*4 + l.
    const size_t rowbase = ((size_t)(b * SEQ + s0) * NM + c * 4 + l) * 1024;
#pragma unroll
    for (int i = 0; i < 16; i++) {
        float mu = smu[i], inv = sinv[i];
        float4 v = *(const float4*)&tile[i][tid * 4];
        ushort4 o;
        o.x = f2bf((v.x - mu) * inv);
        o.y = f2bf((v.y - mu) * inv);
        o.z = f2bf((v.z - mu) * inv);
        o.w = f2bf((v.w - mu) * inv);
        *(ushort4*)(mem_n + rowbase + (size_t)i * NM * 1024 + tid * 4) = o;
    }
}

// ---------------------------------------------------------------------------
// Flash attention (MFMA bf16), 8-wave split-KV:
//   waves 0-3 (group 0) process even kv tiles, waves 4-7 (group 1) odd tiles,
//   same Q rows; states merged at the end via LDS (two-way flash combine).
// ---------------------------------------------------------------------------
#define TQ 64
#define TK 64
__global__ __launch_bounds__(512) void flash_attn_kernel(
    const ushort* __restrict__ qkvb, const float* __restrict__ msc,
    ushort* __restrict__ mergedb, float* __restrict__ wmem)
{
    // 55296 B total: Ks[2][64][72] | Vt[2][64][72] | Ps[8][16][72]
    // cbuf (combine, 4x64x25 f32 = 25600 B) aliases Ks/Vt after the KV loop.
    __shared__ __align__(16) char smem[55296];
    ushort (*Ks)[TK][72]  = (ushort (*)[TK][72])smem;
    ushort (*Vt)[HD][72]  = (ushort (*)[HD][72])(smem + 18432);
    ushort (*Ps)[16][72]  = (ushort (*)[16][72])(smem + 36864);
    float  (*cbuf)[64][25] = (float (*)[64][25])smem;

    const int bxr = blockIdx.x;
    const int qt = (bxr & 1) ? (bxr >> 1) : (15 - (bxr >> 1));
    const int bh = blockIdx.y;
    const int b = bh >> 4, h = bh & 15;
    const int tid = threadIdx.x;
    const int w = tid >> 6;        // 0..7
    const int g = w >> 2;          // kv parity group
    const int wq = w & 3;          // q sub-tile within the 64-row block
    const int lane = tid & 63;
    const int n = lane & 15;
    const int qd = lane >> 4;

    const ushort* qb = qkvb;
    const ushort* kb = qkvb + (size_t)OUTT;
    const ushort* vb = qkvb + (size_t)2 * OUTT;
    const size_t headoff = (size_t)bh * SEQ * HD;

    const int qrow0 = qt * TQ + wq * 16;
    const ushort* qp = qb + headoff + (size_t)(qrow0 + n) * HD;
    short8 qf0 = *(const short8*)(qp + qd * 8);
    short8 qf1 = *(const short8*)(qp + 32 + qd * 8);

    float mrow[4], lrow[4];
    f32x4 Oacc[4];
#pragma unroll
    for (int r = 0; r < 4; r++) { mrow[r] = NEGBIG; lrow[r] = 0.f; }
#pragma unroll
    for (int nt = 0; nt < 4; nt++) Oacc[nt] = (f32x4){0.f, 0.f, 0.f, 0.f};

    // staging indices within each 256-thread group
    const int gtid = tid & 255;
    const int key = gtid >> 2;
    const int c0 = (gtid & 3) * 16;
    const int nsteps = (qt + 2) >> 1;   // ceil((qt+1)/2)

    for (int step = 0; step < nsteps; ++step) {
        const int kt = 2 * step + g;
        const bool act = (kt <= qt);
        if (act) {
            const ushort* kg = kb + headoff + (size_t)(kt * TK + key) * HD + c0;
            *(short8*)&Ks[g][key][c0]     = *(const short8*)kg;
            *(short8*)&Ks[g][key][c0 + 8] = *(const short8*)(kg + 8);
            const ushort* vg = vb + headoff + (size_t)(kt * TK + key) * HD + c0;
            ushort vs[16];
            *(short8*)&vs[0] = *(const short8*)vg;
            *(short8*)&vs[8] = *(const short8*)(vg + 8);
#pragma unroll
            for (int i = 0; i < 16; i++) Vt[g][c0 + i][key] = vs[i];
        }
        __syncthreads();
        if (act) {
            f32x4 sacc[4];
#pragma unroll
            for (int kc = 0; kc < 4; kc++) {
                short8 kf0 = *(const short8*)&Ks[g][kc * 16 + n][qd * 8];
                short8 kf1 = *(const short8*)&Ks[g][kc * 16 + n][32 + qd * 8];
                f32x4 z = (f32x4){0.f, 0.f, 0.f, 0.f};
                z = __builtin_amdgcn_mfma_f32_16x16x32_bf16(qf0, kf0, z, 0, 0, 0);
                z = __builtin_amdgcn_mfma_f32_16x16x32_bf16(qf1, kf1, z, 0, 0, 0);
                sacc[kc] = z;
            }
            const bool diag = (kt == qt);
#pragma unroll
            for (int kc = 0; kc < 4; kc++) {
#pragma unroll
                for (int r = 0; r < 4; r++) {
                    float sv = sacc[kc][r] * 0.125f;
                    if (diag) {
                        int qrow = qrow0 + qd * 4 + r;
                        int kk = kt * TK + kc * 16 + n;
                        if (kk > qrow) sv = NEGBIG;
                    }
                    sacc[kc][r] = sv;
                }
            }
            float alpha[4];
#pragma unroll
            for (int r = 0; r < 4; r++) {
                float mx = fmaxf(fmaxf(sacc[0][r], sacc[1][r]), fmaxf(sacc[2][r], sacc[3][r]));
                mx = fmaxf(mx, __shfl_xor(mx, 1));
                mx = fmaxf(mx, __shfl_xor(mx, 2));
                mx = fmaxf(mx, __shfl_xor(mx, 4));
                mx = fmaxf(mx, __shfl_xor(mx, 8));
                float mnew = fmaxf(mrow[r], mx);
                alpha[r] = __expf(mrow[r] - mnew);
                mrow[r] = mnew;
            }
            float psum[4] = {0.f, 0.f, 0.f, 0.f};
#pragma unroll
            for (int kc = 0; kc < 4; kc++) {
#pragma unroll
                for (int r = 0; r < 4; r++) {
                    float p = __expf(sacc[kc][r] - mrow[r]);
                    psum[r] += p;
                    Ps[w][qd * 4 + r][kc * 16 + n] = f2bf(p);
                }
            }
#pragma unroll
            for (int r = 0; r < 4; r++) {
                float ps = psum[r];
                ps += __shfl_xor(ps, 1);
                ps += __shfl_xor(ps, 2);
                ps += __shfl_xor(ps, 4);
                ps += __shfl_xor(ps, 8);
                lrow[r] = alpha[r] * lrow[r] + ps;
            }
#pragma unroll
            for (int nt = 0; nt < 4; nt++)
#pragma unroll
                for (int r = 0; r < 4; r++)
                    Oacc[nt][r] *= alpha[r];
            short8 pf0 = *(const short8*)&Ps[w][n][qd * 8];
            short8 pf1 = *(const short8*)&Ps[w][n][32 + qd * 8];
#pragma unroll
            for (int nt = 0; nt < 4; nt++) {
                short8 vf0 = *(const short8*)&Vt[g][nt * 16 + n][qd * 8];
                short8 vf1 = *(const short8*)&Vt[g][nt * 16 + n][32 + qd * 8];
                f32x4 z = Oacc[nt];
                z = __builtin_amdgcn_mfma_f32_16x16x32_bf16(pf0, vf0, z, 0, 0, 0);
                z = __builtin_amdgcn_mfma_f32_16x16x32_bf16(pf1, vf1, z, 0, 0, 0);
                Oacc[nt] = z;
            }
        }
        __syncthreads();
    }

    // --- two-way combine: group 1 hands its state to group 0 via LDS ---
    if (g == 1) {
        float* cb = cbuf[wq][lane];
#pragma unroll
        for (int nt = 0; nt < 4; nt++)
#pragma unroll
            for (int r = 0; r < 4; r++) cb[nt * 4 + r] = Oacc[nt][r];
#pragma unroll
        for (int r = 0; r < 4; r++) { cb[16 + r] = mrow[r]; cb[20 + r] = lrow[r]; }
    }
    __syncthreads();
    if (g == 1) return;

    {
        const float* cb = cbuf[wq][lane];
#pragma unroll
        for (int r = 0; r < 4; r++) {
            float m1 = cb[16 + r], l1 = cb[20 + r];
            float mnew = fmaxf(mrow[r], m1);
            float a0 = __expf(mrow[r] - mnew);
            float a1 = __expf(m1 - mnew);
            lrow[r] = a0 * lrow[r] + a1 * l1;
#pragma unroll
            for (int nt = 0; nt < 4; nt++)
                Oacc[nt][r] = a0 * Oacc[nt][r] + a1 * cb[nt * 4 + r];
            mrow[r] = mnew;
        }
    }

#pragma unroll
    for (int r = 0; r < 4; r++) {
        int srow = qrow0 + qd * 4 + r;
        const float* mp = msc + ((size_t)(b * SEQ + srow) * NH + h) * NM;
        float mm = NEGBIG;
#pragma unroll
        for (int j = 0; j < NM; j++) mm = fmaxf(mm, mp[j]);
        float mf = fmaxf(mrow[r], mm);
        float al = __expf(mrow[r] - mf);
        float msum = 0.f;
#pragma unroll
        for (int j = 0; j < NM; j++) msum += __expf(mp[j] - mf);
        float lf = al * lrow[r] + msum;
        float inv = 1.f / lf;
        float scale = al * inv;
        ushort* mrow_out = mergedb + (size_t)(b * SEQ + srow) * DIM + h * HD;
#pragma unroll
        for (int nt = 0; nt < 4; nt++)
            mrow_out[nt * 16 + n] = f2bf(Oacc[nt][r] * scale);
        size_t wb = ((size_t)(b * SEQ + srow) * NH + h) * 16;
        if (n < 12)       wmem[wb + n]  = __expf(mp[n] - mf) * inv;
        else if (n == 12) wmem[wb + 12] = msum * inv;
    }
}

// ---------------------------------------------------------------------------
// wvec[bs,h,:] = sum_m wmem[bs,h,m] * mem_n[bs,m,:]  (bf16 out)
// ---------------------------------------------------------------------------
__global__ __launch_bounds__(256) void wvec_kernel(
    const float* __restrict__ wmem, const ushort* __restrict__ mem_n,
    ushort* __restrict__ wvecb)
{
    __shared__ ushort memL[NM][1032];
    __shared__ float wL[NH][NM];
    const int bs = blockIdx.x;
    const int tid = threadIdx.x;

    for (int t = tid; t < NM * 256; t += 256) {
        int m = t >> 8, c4 = (t & 255) << 2;
        *(ushort4*)&memL[m][c4] = *(const ushort4*)(mem_n + ((size_t)bs * NM + m) * 1024 + c4);
    }
    if (tid < NH * NM) {
        int h = tid / NM, m = tid % NM;
        wL[h][m] = wmem[((size_t)bs * NH + h) * 16 + m];
    }
    __syncthreads();

    for (int h = 0; h < NH; h++) {
#pragma unroll
        for (int c0 = 0; c0 < 1024; c0 += 256) {
            int c = c0 + tid;
            float acc = 0.f;
#pragma unroll
            for (int m = 0; m < NM; m++)
                acc = fmaf(wL[h][m], bf2f(memL[m][c]), acc);
            wvecb[((size_t)bs * NH + h) * 1024 + c] = f2bf(acc);
        }
    }
}

// ---------------------------------------------------------------------------
extern "C" void kernel_launch(void* const* d_in, const int* in_sizes, int n_in,
                              void* d_out, int out_size, void* d_ws, size_t ws_size,
                              hipStream_t stream) {
    const float* x    = (const float*)d_in[0];
    const float* pk   = (const float*)d_in[1];
    const float* pv   = (const float*)d_in[2];
    const float* pq   = (const float*)d_in[3];
    const float* Wqkv = (const float*)d_in[4];
    const float* bqkv = (const float*)d_in[5];
    const float* Wout = (const float*)d_in[6];
    const float* bout = (const float*)d_in[7];
    float* out = (float*)d_out;

    // ws: mem_n 50.3 | qproj/wvecb 67.1 (aliased) | msc 1.6 | wmem 2.1 |
    //     qkvb 12.6 | Wqkvb 6.3 | Woutb 2.1 | xb/mergedb 4.2 (aliased) ~146 MB
    ushort* mem_n  = (ushort*)d_ws;
    ushort* qproj  = mem_n + (size_t)MEMROWS * 1024;
    ushort* wvecb  = qproj;                                 // alias: qproj dead after msc
    float*  msc    = (float*)(qproj + (size_t)NTOK * NH * 1024);
    float*  wmem   = msc + (size_t)NTOK * NH * NM;
    ushort* qkvb   = (ushort*)(wmem + (size_t)NTOK * NH * 16);
    ushort* Wqkvb  = qkvb + (size_t)3 * OUTT;
    ushort* Woutb  = Wqkvb + (size_t)3072 * 1024;
    ushort* xb     = Woutb + (size_t)1024 * 1024;
    ushort* mergedb = xb;                                   // alias: xb dead after qkv gemm

    const int na4 = NTOK * DIM / 4, nb4 = 3 * DIM * DIM / 4, nc4 = DIM * DIM / 4;

    // 1. bf16 conversions
    cvt3_kernel<<<(na4 + nb4 + nc4 + 255) / 256, 256, 0, stream>>>(
        x, xb, na4, Wqkv, Wqkvb, nb4, Wout, Woutb, nc4);
    // 2. qkv GEMM (MFMA) -> d_out fp32 k,v,q + qkvb bf16
    mfma_qkv_kernel<<<dim3(24, 16), 256, 0, stream>>>(xb, Wqkvb, bqkv, out, qkvb);
    // 3. layernorm of mem rows -> bf16 (contiguous-read, LDS tile)
    ln_mem_kernel<<<3 * 4 * BATCH * (SEQ / 16), 256, 0, stream>>>(pq, pk, pv, mem_n);
    // 4. qproj (MFMA, per head)
    mfma_qproj_kernel<<<dim3(8, 16, NH), 256, 0, stream>>>(
        qkvb, Wqkvb + (size_t)DIM * DIM, qproj);
    // 5. mem scores (fused MFMA per token)
    msc_fused_kernel<<<NTOK / 4, 256, 0, stream>>>(qproj, mem_n, qkvb, bqkv, msc);
    // 6. flash attention (8-wave split-KV) -> mergedb bf16, wmem
    flash_attn_kernel<<<dim3(16, 32), 512, 0, stream>>>(qkvb, msc, mergedb, wmem);
    // 7. wvec
    wvec_kernel<<<NTOK, 256, 0, stream>>>(wmem, mem_n, wvecb);
    // 8. vproj (MFMA, per head): mergedb += wvec@Wv^T + wsum*bv (in place)
    mfma_vproj_kernel<<<dim3(16, NH), 256, 0, stream>>>(
        wvecb, Wqkvb + (size_t)2 * DIM * DIM, bqkv + 2 * DIM, wmem, mergedb);
    // 9. out GEMM (MFMA) -> d_out fp32
    mfma_out_kernel<<<dim3(8, 16), 256, 0, stream>>>(mergedb, Woutb, bout, out);
}

// Round 5
// 360.449 us; speedup vs baseline: 1.0143x; 1.0143x over previous
//
#include <hip/hip_runtime.h>

// Problem constants (B=2, S=1024, D=1024, H=16, hd=64, L=4, M=12)
#define BATCH 2
#define SEQ   1024
#define DIM   1024
#define NH    16
#define HD    64
#define NM    12
#define NTOK  (BATCH*SEQ)          // 2048
#define MEMROWS (BATCH*SEQ*NM)     // 24576
#define OUTT  2097152              // elements per output tensor
#define NEGBIG (-1.0e30f)

typedef __attribute__((ext_vector_type(8))) short short8;   // 8 bf16 (4 VGPRs)
typedef __attribute__((ext_vector_type(4))) float f32x4;    // MFMA C/D

__device__ __forceinline__ float bf2f(ushort u) {
    union { unsigned int i; float f; } t; t.i = ((unsigned int)u) << 16; return t.f;
}
__device__ __forceinline__ ushort f2bf(float f) {
    union { float f; unsigned int i; } t; t.f = f;
    unsigned int i = t.i;
    unsigned int lsb = (i >> 16) & 1u;
    i += 0x7fffu + lsb;
    return (ushort)(i >> 16);
}

// ---------------------------------------------------------------------------
// fp32 -> bf16 conversion for x, Wqkv, Wout (one pass, float4-vectorized)
// ---------------------------------------------------------------------------
__global__ __launch_bounds__(256) void cvt3_kernel(
    const float* __restrict__ a, ushort* __restrict__ ab, int na4,
    const float* __restrict__ b, ushort* __restrict__ bb, int nb4,
    const float* __restrict__ c, ushort* __restrict__ cb, int nc4)
{
    int i = blockIdx.x * 256 + threadIdx.x;
    if (i >= na4 + nb4 + nc4) return;
    const float* src; ushort* dst; int j;
    if (i < na4)            { src = a; dst = ab; j = i; }
    else if (i < na4 + nb4) { src = b; dst = bb; j = i - na4; }
    else                    { src = c; dst = cb; j = i - na4 - nb4; }
    float4 v = ((const float4*)src)[j];
    ushort4 o; o.x = f2bf(v.x); o.y = f2bf(v.y); o.z = f2bf(v.z); o.w = f2bf(v.w);
    ((ushort4*)dst)[j] = o;
}

// ---------------------------------------------------------------------------
// MFMA GEMM core conventions (verified):
//  A-frag: m=lane&15, k=qd*8+j ; B-frag: n=lane&15, k=qd*8+j
//  C/D:    col=lane&15, row=qd*4+reg
// LDS tiles padded to 40 elems/row (80 B, 16B-aligned).
// ---------------------------------------------------------------------------

// ---------------------------------------------------------------------------
// FUSED qkv GEMM + LayerNorm(mem rows) — heterogeneous blocks.
// Blocks 0..383: qkv GEMM [2048x1024]x[3072x1024]^T + bias -> fp32 kvq + bf16.
// Blocks 384..6527: LN of 4 mem rows each (wave-per-row, 0 LDS, shfl reduce).
// Rationale (R2-R4 evidence): ln_mem is pinned at ~2.1 TB/s regardless of
// structure (memory-system wall); qkv GEMM is MFMA-bound with idle HBM.
// Co-scheduling overlaps them; ln's 47us hides under the GEMM.
// ---------------------------------------------------------------------------
#define QKV_BLKS 384
__global__ __launch_bounds__(256) void qkv_ln_fused_kernel(
    const ushort* __restrict__ xb, const ushort* __restrict__ Wb,
    const float* __restrict__ bias, float* __restrict__ out,
    ushort* __restrict__ qkvb,
    const float* __restrict__ pq, const float* __restrict__ pk,
    const float* __restrict__ pv, ushort* __restrict__ mem_n)
{
    const int bid = blockIdx.x;
    const int tid = threadIdx.x;
    if (bid < QKV_BLKS) {
        // ---------------- qkv GEMM path ----------------
        __shared__ ushort As[128][40];
        __shared__ ushort Bs[128][40];
        const int w = tid >> 6, lane = tid & 63;
        const int n = lane & 15, qd = lane >> 4;
        const int wr = (w >> 1) * 64, wc = (w & 1) * 64;
        const int row0 = (bid / 24) * 128, col0 = (bid % 24) * 128;
        const int r1 = tid >> 2, o1 = (tid & 3) * 8;
        const int r2 = (tid + 256) >> 2, o2 = ((tid + 256) & 3) * 8;

        f32x4 acc[4][4];
#pragma unroll
        for (int mt = 0; mt < 4; mt++)
#pragma unroll
            for (int nt = 0; nt < 4; nt++) acc[mt][nt] = (f32x4){0.f, 0.f, 0.f, 0.f};

        for (int k0 = 0; k0 < 1024; k0 += 32) {
            *(short8*)&As[r1][o1] = *(const short8*)(xb + (size_t)(row0 + r1) * 1024 + k0 + o1);
            *(short8*)&As[r2][o2] = *(const short8*)(xb + (size_t)(row0 + r2) * 1024 + k0 + o2);
            *(short8*)&Bs[r1][o1] = *(const short8*)(Wb + (size_t)(col0 + r1) * 1024 + k0 + o1);
            *(short8*)&Bs[r2][o2] = *(const short8*)(Wb + (size_t)(col0 + r2) * 1024 + k0 + o2);
            __syncthreads();
            short8 af[4], bf[4];
#pragma unroll
            for (int mt = 0; mt < 4; mt++) af[mt] = *(const short8*)&As[wr + mt * 16 + n][qd * 8];
#pragma unroll
            for (int nt = 0; nt < 4; nt++) bf[nt] = *(const short8*)&Bs[wc + nt * 16 + n][qd * 8];
#pragma unroll
            for (int mt = 0; mt < 4; mt++)
#pragma unroll
                for (int nt = 0; nt < 4; nt++)
                    acc[mt][nt] = __builtin_amdgcn_mfma_f32_16x16x32_bf16(af[mt], bf[nt], acc[mt][nt], 0, 0, 0);
            __syncthreads();
        }
#pragma unroll
        for (int mt = 0; mt < 4; mt++)
#pragma unroll
            for (int nt = 0; nt < 4; nt++)
#pragma unroll
                for (int r = 0; r < 4; r++) {
                    int row = row0 + wr + mt * 16 + qd * 4 + r;
                    int col = col0 + wc + nt * 16 + n;
                    float val = acc[mt][nt][r] + bias[col];
                    int t = col >> 10, h = (col >> 6) & 15, d = col & 63;
                    int b = row >> 10, s = row & 1023;
                    size_t idx = (((size_t)(b * NH + h) * SEQ + s) * HD) + d;
                    size_t base = (t == 0) ? (size_t)3 * OUTT : (t == 1) ? (size_t)OUTT : (size_t)2 * OUTT;
                    out[base + idx] = val;
                    qkvb[(size_t)t * OUTT + idx] = f2bf(val);
                }
    } else {
        // ---------------- LayerNorm path (wave per row) ----------------
        const int wid = tid >> 6, lane = tid & 63;
        const int r = (bid - QKV_BLKS) * 4 + wid;   // mem row 0..24575
        const int idx = r % NM;
        const int bs = r / NM;
        const int s = bs & (SEQ - 1);
        const int b = bs >> 10;
        const int c = idx >> 2;                  // 0=q 1=k 2=v
        const int l = idx & 3;                   // layer
        const float* src = (c == 0) ? pq : ((c == 1) ? pk : pv);
        const size_t base = ((size_t)(l * BATCH + b) * NH) * (SEQ * HD) + (size_t)s * HD;

        float4 v4[4];
        float sum = 0.f, sumsq = 0.f;
#pragma unroll
        for (int p = 0; p < 4; p++) {
            int h = p * 4 + (lane >> 4);
            int d = (lane & 15) * 4;
            float4 v = *(const float4*)(src + base + (size_t)h * (SEQ * HD) + d);
            v4[p] = v;
            sum   += v.x + v.y + v.z + v.w;
            sumsq += v.x * v.x + v.y * v.y + v.z * v.z + v.w * v.w;
        }
#pragma unroll
        for (int off = 32; off > 0; off >>= 1) {
            sum   += __shfl_xor(sum, off);
            sumsq += __shfl_xor(sumsq, off);
        }
        float mu  = sum * (1.f / 1024.f);
        float var = fmaxf(sumsq * (1.f / 1024.f) - mu * mu, 0.f);
        float inv = rsqrtf(var + 1e-5f);
        ushort* dst = mem_n + (size_t)r * 1024;
#pragma unroll
        for (int p = 0; p < 4; p++) {
            int dp = (p * 64 + lane) * 4;
            ushort4 o;
            o.x = f2bf((v4[p].x - mu) * inv);
            o.y = f2bf((v4[p].y - mu) * inv);
            o.z = f2bf((v4[p].z - mu) * inv);
            o.w = f2bf((v4[p].w - mu) * inv);
            *(ushort4*)(dst + dp) = o;
        }
    }
}

// out GEMM: mergedb[2048x1024] x Woutb[1024x1024]^T + bout -> d_out fp32
__global__ __launch_bounds__(256) void mfma_out_kernel(
    const ushort* __restrict__ Ab, const ushort* __restrict__ Wb,
    const float* __restrict__ bias, float* __restrict__ C)
{
    __shared__ ushort As[128][40];
    __shared__ ushort Bs[128][40];
    const int tid = threadIdx.x;
    const int w = tid >> 6, lane = tid & 63;
    const int n = lane & 15, qd = lane >> 4;
    const int wr = (w >> 1) * 64, wc = (w & 1) * 64;
    const int row0 = blockIdx.y * 128, col0 = blockIdx.x * 128;
    const int r1 = tid >> 2, o1 = (tid & 3) * 8;
    const int r2 = (tid + 256) >> 2, o2 = ((tid + 256) & 3) * 8;

    f32x4 acc[4][4];
#pragma unroll
    for (int mt = 0; mt < 4; mt++)
#pragma unroll
        for (int nt = 0; nt < 4; nt++) acc[mt][nt] = (f32x4){0.f, 0.f, 0.f, 0.f};

    for (int k0 = 0; k0 < 1024; k0 += 32) {
        *(short8*)&As[r1][o1] = *(const short8*)(Ab + (size_t)(row0 + r1) * 1024 + k0 + o1);
        *(short8*)&As[r2][o2] = *(const short8*)(Ab + (size_t)(row0 + r2) * 1024 + k0 + o2);
        *(short8*)&Bs[r1][o1] = *(const short8*)(Wb + (size_t)(col0 + r1) * 1024 + k0 + o1);
        *(short8*)&Bs[r2][o2] = *(const short8*)(Wb + (size_t)(col0 + r2) * 1024 + k0 + o2);
        __syncthreads();
        short8 af[4], bf[4];
#pragma unroll
        for (int mt = 0; mt < 4; mt++) af[mt] = *(const short8*)&As[wr + mt * 16 + n][qd * 8];
#pragma unroll
        for (int nt = 0; nt < 4; nt++) bf[nt] = *(const short8*)&Bs[wc + nt * 16 + n][qd * 8];
#pragma unroll
        for (int mt = 0; mt < 4; mt++)
#pragma unroll
            for (int nt = 0; nt < 4; nt++)
                acc[mt][nt] = __builtin_amdgcn_mfma_f32_16x16x32_bf16(af[mt], bf[nt], acc[mt][nt], 0, 0, 0);
        __syncthreads();
    }
#pragma unroll
    for (int mt = 0; mt < 4; mt++)
#pragma unroll
        for (int nt = 0; nt < 4; nt++)
#pragma unroll
            for (int r = 0; r < 4; r++) {
                int row = row0 + wr + mt * 16 + qd * 4 + r;
                int col = col0 + wc + nt * 16 + n;
                C[(size_t)row * 1024 + col] = acc[mt][nt][r] + bias[col];
            }
}

// qproj per head: q_h[2048x64] @ WkBlock_h[64x1024] -> qproj bf16 (B transposed on stage)
__global__ __launch_bounds__(256) void mfma_qproj_kernel(
    const ushort* __restrict__ qkvb, const ushort* __restrict__ Wkb,
    ushort* __restrict__ qproj)
{
    __shared__ ushort As[128][40];
    __shared__ ushort Bs[128][40];
    const int tid = threadIdx.x;
    const int w = tid >> 6, lane = tid & 63;
    const int n = lane & 15, qd = lane >> 4;
    const int wr = (w >> 1) * 64, wc = (w & 1) * 64;
    const int row0 = blockIdx.y * 128, col0 = blockIdx.x * 128;
    const int h = blockIdx.z;
    const int b = row0 >> 10, s0 = row0 & 1023;
    const ushort* Abase = qkvb + ((size_t)(b * NH + h) * SEQ + s0) * HD;
    const int r1 = tid >> 2, o1 = (tid & 3) * 8;
    const int r2 = (tid + 256) >> 2, o2 = ((tid + 256) & 3) * 8;
    const int bkk = tid >> 3, bc0 = (tid & 7) * 16;

    f32x4 acc[4][4];
#pragma unroll
    for (int mt = 0; mt < 4; mt++)
#pragma unroll
        for (int nt = 0; nt < 4; nt++) acc[mt][nt] = (f32x4){0.f, 0.f, 0.f, 0.f};

    for (int k0 = 0; k0 < 64; k0 += 32) {
        *(short8*)&As[r1][o1] = *(const short8*)(Abase + (size_t)r1 * HD + k0 + o1);
        *(short8*)&As[r2][o2] = *(const short8*)(Abase + (size_t)r2 * HD + k0 + o2);
        // B transpose stage: Bs[c][kk] = Wk[h*64+k0+kk][col0+c]
        {
            const ushort* bsrc = Wkb + (size_t)(h * HD + k0 + bkk) * 1024 + col0 + bc0;
            ushort tmp[16];
            *(short8*)&tmp[0] = *(const short8*)bsrc;
            *(short8*)&tmp[8] = *(const short8*)(bsrc + 8);
#pragma unroll
            for (int i = 0; i < 16; i++) Bs[bc0 + i][bkk] = tmp[i];
        }
        __syncthreads();
        short8 af[4], bf[4];
#pragma unroll
        for (int mt = 0; mt < 4; mt++) af[mt] = *(const short8*)&As[wr + mt * 16 + n][qd * 8];
#pragma unroll
        for (int nt = 0; nt < 4; nt++) bf[nt] = *(const short8*)&Bs[wc + nt * 16 + n][qd * 8];
#pragma unroll
        for (int mt = 0; mt < 4; mt++)
#pragma unroll
            for (int nt = 0; nt < 4; nt++)
                acc[mt][nt] = __builtin_amdgcn_mfma_f32_16x16x32_bf16(af[mt], bf[nt], acc[mt][nt], 0, 0, 0);
        __syncthreads();
    }
#pragma unroll
    for (int mt = 0; mt < 4; mt++)
#pragma unroll
        for (int nt = 0; nt < 4; nt++)
#pragma unroll
            for (int r = 0; r < 4; r++) {
                int token = row0 + wr + mt * 16 + qd * 4 + r;
                int col = col0 + wc + nt * 16 + n;
                qproj[((size_t)token * NH + h) * 1024 + col] = f2bf(acc[mt][nt][r]);
            }
}

// vproj per head: merged[t, h*64+d] += wvec_h[t,:]·Wv[h*64+d,:] + wsum*bv (in-place bf16)
__global__ __launch_bounds__(256) void mfma_vproj_kernel(
    const ushort* __restrict__ wvecb, const ushort* __restrict__ Wvb,
    const float* __restrict__ bv, const float* __restrict__ wmem,
    ushort* __restrict__ mergedb)
{
    __shared__ ushort As[128][40];
    __shared__ ushort Bs[64][40];
    const int tid = threadIdx.x;
    const int w = tid >> 6, lane = tid & 63;
    const int n = lane & 15, qd = lane >> 4;
    const int wr = (w >> 1) * 64, wc = (w & 1) * 32;
    const int row0 = blockIdx.x * 128;
    const int h = blockIdx.y;
    const int r1 = tid >> 2, o1 = (tid & 3) * 8;
    const int r2 = (tid + 256) >> 2, o2 = ((tid + 256) & 3) * 8;

    f32x4 acc[4][2];
#pragma unroll
    for (int mt = 0; mt < 4; mt++)
#pragma unroll
        for (int nt = 0; nt < 2; nt++) acc[mt][nt] = (f32x4){0.f, 0.f, 0.f, 0.f};

    for (int k0 = 0; k0 < 1024; k0 += 32) {
        *(short8*)&As[r1][o1] = *(const short8*)(wvecb + ((size_t)(row0 + r1) * NH + h) * 1024 + k0 + o1);
        *(short8*)&As[r2][o2] = *(const short8*)(wvecb + ((size_t)(row0 + r2) * NH + h) * 1024 + k0 + o2);
        *(short8*)&Bs[r1 & 63][o1] = *(const short8*)(Wvb + (size_t)(h * HD + (r1 & 63)) * 1024 + k0 + o1);
        __syncthreads();
        short8 af[4], bf[2];
#pragma unroll
        for (int mt = 0; mt < 4; mt++) af[mt] = *(const short8*)&As[wr + mt * 16 + n][qd * 8];
#pragma unroll
        for (int nt = 0; nt < 2; nt++) bf[nt] = *(const short8*)&Bs[wc + nt * 16 + n][qd * 8];
#pragma unroll
        for (int mt = 0; mt < 4; mt++)
#pragma unroll
            for (int nt = 0; nt < 2; nt++)
                acc[mt][nt] = __builtin_amdgcn_mfma_f32_16x16x32_bf16(af[mt], bf[nt], acc[mt][nt], 0, 0, 0);
        __syncthreads();
    }
#pragma unroll
    for (int mt = 0; mt < 4; mt++)
#pragma unroll
        for (int nt = 0; nt < 2; nt++)
#pragma unroll
            for (int r = 0; r < 4; r++) {
                int token = row0 + wr + mt * 16 + qd * 4 + r;
                int d = wc + nt * 16 + n;
                float ws = wmem[((size_t)token * NH + h) * 16 + 12];
                size_t mi = (size_t)token * DIM + h * HD + d;
                float val = bf2f(mergedb[mi]) + acc[mt][nt][r] + ws * bv[h * HD + d];
                mergedb[mi] = f2bf(val);
            }
}

// mem_scores fused: per token, D[h][m] = qproj_h · mem_m via one MFMA chain.
__global__ __launch_bounds__(256) void msc_fused_kernel(
    const ushort* __restrict__ qproj, const ushort* __restrict__ mem_n,
    const ushort* __restrict__ qkvb, const float* __restrict__ bqkv,
    float* __restrict__ msc)
{
    const int tid = threadIdx.x;
    const int w = tid >> 6, lane = tid & 63;
    const int n = lane & 15, qd = lane >> 4;
    const int bs = blockIdx.x * 4 + w;

    float qbk = 0.f;
    if (lane < 16) {
        int b = bs >> 10, s = bs & 1023;
        const ushort* qrow = qkvb + ((size_t)(b * NH + lane) * SEQ + s) * HD;
        const float* bk = bqkv + DIM + lane * HD;
#pragma unroll
        for (int d = 0; d < HD; d++) qbk += bf2f(qrow[d]) * bk[d];
    }
    f32x4 acc = (f32x4){0.f, 0.f, 0.f, 0.f};
    const ushort* qpB = qproj + ((size_t)bs * NH + n) * 1024;
    const int mrow = (n < NM) ? n : 0;
    const ushort* mmB = mem_n + ((size_t)bs * NM + mrow) * 1024;
    for (int k0 = 0; k0 < 1024; k0 += 32) {
        short8 af = *(const short8*)(qpB + k0 + qd * 8);
        short8 bf = *(const short8*)(mmB + k0 + qd * 8);
        acc = __builtin_amdgcn_mfma_f32_16x16x32_bf16(af, bf, acc, 0, 0, 0);
    }
#pragma unroll
    for (int r = 0; r < 4; r++) {
        int h = qd * 4 + r;
        float qb = __shfl(qbk, h);
        if (n < NM)
            msc[((size_t)bs * NH + h) * NM + n] = 0.125f * (acc[r] + qb);
    }
}

// ---------------------------------------------------------------------------
// Flash attention (MFMA bf16), 8-wave split-KV:
//   waves 0-3 (group 0) process even kv tiles, waves 4-7 (group 1) odd tiles,
//   same Q rows; states merged at the end via LDS (two-way flash combine).
// ---------------------------------------------------------------------------
#define TQ 64
#define TK 64
__global__ __launch_bounds__(512) void flash_attn_kernel(
    const ushort* __restrict__ qkvb, const float* __restrict__ msc,
    ushort* __restrict__ mergedb, float* __restrict__ wmem)
{
    // 55296 B total: Ks[2][64][72] | Vt[2][64][72] | Ps[8][16][72]
    // cbuf (combine, 4x64x25 f32 = 25600 B) aliases Ks/Vt after the KV loop.
    __shared__ __align__(16) char smem[55296];
    ushort (*Ks)[TK][72]  = (ushort (*)[TK][72])smem;
    ushort (*Vt)[HD][72]  = (ushort (*)[HD][72])(smem + 18432);
    ushort (*Ps)[16][72]  = (ushort (*)[16][72])(smem + 36864);
    float  (*cbuf)[64][25] = (float (*)[64][25])smem;

    const int bxr = blockIdx.x;
    const int qt = (bxr & 1) ? (bxr >> 1) : (15 - (bxr >> 1));
    const int bh = blockIdx.y;
    const int b = bh >> 4, h = bh & 15;
    const int tid = threadIdx.x;
    const int w = tid >> 6;        // 0..7
    const int g = w >> 2;          // kv parity group
    const int wq = w & 3;          // q sub-tile within the 64-row block
    const int lane = tid & 63;
    const int n = lane & 15;
    const int qd = lane >> 4;

    const ushort* qb = qkvb;
    const ushort* kb = qkvb + (size_t)OUTT;
    const ushort* vb = qkvb + (size_t)2 * OUTT;
    const size_t headoff = (size_t)bh * SEQ * HD;

    const int qrow0 = qt * TQ + wq * 16;
    const ushort* qp = qb + headoff + (size_t)(qrow0 + n) * HD;
    short8 qf0 = *(const short8*)(qp + qd * 8);
    short8 qf1 = *(const short8*)(qp + 32 + qd * 8);

    float mrow[4], lrow[4];
    f32x4 Oacc[4];
#pragma unroll
    for (int r = 0; r < 4; r++) { mrow[r] = NEGBIG; lrow[r] = 0.f; }
#pragma unroll
    for (int nt = 0; nt < 4; nt++) Oacc[nt] = (f32x4){0.f, 0.f, 0.f, 0.f};

    // staging indices within each 256-thread group
    const int gtid = tid & 255;
    const int key = gtid >> 2;
    const int c0 = (gtid & 3) * 16;
    const int nsteps = (qt + 2) >> 1;   // ceil((qt+1)/2)

    for (int step = 0; step < nsteps; ++step) {
        const int kt = 2 * step + g;
        const bool act = (kt <= qt);
        if (act) {
            const ushort* kg = kb + headoff + (size_t)(kt * TK + key) * HD + c0;
            *(short8*)&Ks[g][key][c0]     = *(const short8*)kg;
            *(short8*)&Ks[g][key][c0 + 8] = *(const short8*)(kg + 8);
            const ushort* vg = vb + headoff + (size_t)(kt * TK + key) * HD + c0;
            ushort vs[16];
            *(short8*)&vs[0] = *(const short8*)vg;
            *(short8*)&vs[8] = *(const short8*)(vg + 8);
#pragma unroll
            for (int i = 0; i < 16; i++) Vt[g][c0 + i][key] = vs[i];
        }
        __syncthreads();
        if (act) {
            f32x4 sacc[4];
#pragma unroll
            for (int kc = 0; kc < 4; kc++) {
                short8 kf0 = *(const short8*)&Ks[g][kc * 16 + n][qd * 8];
                short8 kf1 = *(const short8*)&Ks[g][kc * 16 + n][32 + qd * 8];
                f32x4 z = (f32x4){0.f, 0.f, 0.f, 0.f};
                z = __builtin_amdgcn_mfma_f32_16x16x32_bf16(qf0, kf0, z, 0, 0, 0);
                z = __builtin_amdgcn_mfma_f32_16x16x32_bf16(qf1, kf1, z, 0, 0, 0);
                sacc[kc] = z;
            }
            const bool diag = (kt == qt);
#pragma unroll
            for (int kc = 0; kc < 4; kc++) {
#pragma unroll
                for (int r = 0; r < 4; r++) {
                    float sv = sacc[kc][r] * 0.125f;
                    if (diag) {
                        int qrow = qrow0 + qd * 4 + r;
                        int kk = kt * TK + kc * 16 + n;
                        if (kk > qrow) sv = NEGBIG;
                    }
                    sacc[kc][r] = sv;
                }
            }
            float alpha[4];
#pragma unroll
            for (int r = 0; r < 4; r++) {
                float mx = fmaxf(fmaxf(sacc[0][r], sacc[1][r]), fmaxf(sacc[2][r], sacc[3][r]));
                mx = fmaxf(mx, __shfl_xor(mx, 1));
                mx = fmaxf(mx, __shfl_xor(mx, 2));
                mx = fmaxf(mx, __shfl_xor(mx, 4));
                mx = fmaxf(mx, __shfl_xor(mx, 8));
                float mnew = fmaxf(mrow[r], mx);
                alpha[r] = __expf(mrow[r] - mnew);
                mrow[r] = mnew;
            }
            float psum[4] = {0.f, 0.f, 0.f, 0.f};
#pragma unroll
            for (int kc = 0; kc < 4; kc++) {
#pragma unroll
                for (int r = 0; r < 4; r++) {
                    float p = __expf(sacc[kc][r] - mrow[r]);
                    psum[r] += p;
                    Ps[w][qd * 4 + r][kc * 16 + n] = f2bf(p);
                }
            }
#pragma unroll
            for (int r = 0; r < 4; r++) {
                float ps = psum[r];
                ps += __shfl_xor(ps, 1);
                ps += __shfl_xor(ps, 2);
                ps += __shfl_xor(ps, 4);
                ps += __shfl_xor(ps, 8);
                lrow[r] = alpha[r] * lrow[r] + ps;
            }
#pragma unroll
            for (int nt = 0; nt < 4; nt++)
#pragma unroll
                for (int r = 0; r < 4; r++)
                    Oacc[nt][r] *= alpha[r];
            short8 pf0 = *(const short8*)&Ps[w][n][qd * 8];
            short8 pf1 = *(const short8*)&Ps[w][n][32 + qd * 8];
#pragma unroll
            for (int nt = 0; nt < 4; nt++) {
                short8 vf0 = *(const short8*)&Vt[g][nt * 16 + n][qd * 8];
                short8 vf1 = *(const short8*)&Vt[g][nt * 16 + n][32 + qd * 8];
                f32x4 z = Oacc[nt];
                z = __builtin_amdgcn_mfma_f32_16x16x32_bf16(pf0, vf0, z, 0, 0, 0);
                z = __builtin_amdgcn_mfma_f32_16x16x32_bf16(pf1, vf1, z, 0, 0, 0);
                Oacc[nt] = z;
            }
        }
        __syncthreads();
    }

    // --- two-way combine: group 1 hands its state to group 0 via LDS ---
    if (g == 1) {
        float* cb = cbuf[wq][lane];
#pragma unroll
        for (int nt = 0; nt < 4; nt++)
#pragma unroll
            for (int r = 0; r < 4; r++) cb[nt * 4 + r] = Oacc[nt][r];
#pragma unroll
        for (int r = 0; r < 4; r++) { cb[16 + r] = mrow[r]; cb[20 + r] = lrow[r]; }
    }
    __syncthreads();
    if (g == 1) return;

    {
        const float* cb = cbuf[wq][lane];
#pragma unroll
        for (int r = 0; r < 4; r++) {
            float m1 = cb[16 + r], l1 = cb[20 + r];
            float mnew = fmaxf(mrow[r], m1);
            float a0 = __expf(mrow[r] - mnew);
            float a1 = __expf(m1 - mnew);
            lrow[r] = a0 * lrow[r] + a1 * l1;
#pragma unroll
            for (int nt = 0; nt < 4; nt++)
                Oacc[nt][r] = a0 * Oacc[nt][r] + a1 * cb[nt * 4 + r];
            mrow[r] = mnew;
        }
    }

#pragma unroll
    for (int r = 0; r < 4; r++) {
        int srow = qrow0 + qd * 4 + r;
        const float* mp = msc + ((size_t)(b * SEQ + srow) * NH + h) * NM;
        float mm = NEGBIG;
#pragma unroll
        for (int j = 0; j < NM; j++) mm = fmaxf(mm, mp[j]);
        float mf = fmaxf(mrow[r], mm);
        float al = __expf(mrow[r] - mf);
        float msum = 0.f;
#pragma unroll
        for (int j = 0; j < NM; j++) msum += __expf(mp[j] - mf);
        float lf = al * lrow[r] + msum;
        float inv = 1.f / lf;
        float scale = al * inv;
        ushort* mrow_out = mergedb + (size_t)(b * SEQ + srow) * DIM + h * HD;
#pragma unroll
        for (int nt = 0; nt < 4; nt++)
            mrow_out[nt * 16 + n] = f2bf(Oacc[nt][r] * scale);
        size_t wb = ((size_t)(b * SEQ + srow) * NH + h) * 16;
        if (n < 12)       wmem[wb + n]  = __expf(mp[n] - mf) * inv;
        else if (n == 12) wmem[wb + 12] = msum * inv;
    }
}

// ---------------------------------------------------------------------------
// wvec[bs,h,:] = sum_m wmem[bs,h,m] * mem_n[bs,m,:]  (bf16 out)
// ---------------------------------------------------------------------------
__global__ __launch_bounds__(256) void wvec_kernel(
    const float* __restrict__ wmem, const ushort* __restrict__ mem_n,
    ushort* __restrict__ wvecb)
{
    __shared__ ushort memL[NM][1032];
    __shared__ float wL[NH][NM];
    const int bs = blockIdx.x;
    const int tid = threadIdx.x;

    for (int t = tid; t < NM * 256; t += 256) {
        int m = t >> 8, c4 = (t & 255) << 2;
        *(ushort4*)&memL[m][c4] = *(const ushort4*)(mem_n + ((size_t)bs * NM + m) * 1024 + c4);
    }
    if (tid < NH * NM) {
        int h = tid / NM, m = tid % NM;
        wL[h][m] = wmem[((size_t)bs * NH + h) * 16 + m];
    }
    __syncthreads();

    for (int h = 0; h < NH; h++) {
#pragma unroll
        for (int c0 = 0; c0 < 1024; c0 += 256) {
            int c = c0 + tid;
            float acc = 0.f;
#pragma unroll
            for (int m = 0; m < NM; m++)
                acc = fmaf(wL[h][m], bf2f(memL[m][c]), acc);
            wvecb[((size_t)bs * NH + h) * 1024 + c] = f2bf(acc);
        }
    }
}

// ---------------------------------------------------------------------------
extern "C" void kernel_launch(void* const* d_in, const int* in_sizes, int n_in,
                              void* d_out, int out_size, void* d_ws, size_t ws_size,
                              hipStream_t stream) {
    const float* x    = (const float*)d_in[0];
    const float* pk   = (const float*)d_in[1];
    const float* pv   = (const float*)d_in[2];
    const float* pq   = (const float*)d_in[3];
    const float* Wqkv = (const float*)d_in[4];
    const float* bqkv = (const float*)d_in[5];
    const float* Wout = (const float*)d_in[6];
    const float* bout = (const float*)d_in[7];
    float* out = (float*)d_out;

    // ws: mem_n 50.3 | qproj/wvecb 67.1 (aliased) | msc 1.6 | wmem 2.1 |
    //     qkvb 12.6 | Wqkvb 6.3 | Woutb 2.1 | xb/mergedb 4.2 (aliased) ~146 MB
    ushort* mem_n  = (ushort*)d_ws;
    ushort* qproj  = mem_n + (size_t)MEMROWS * 1024;
    ushort* wvecb  = qproj;                                 // alias: qproj dead after msc
    float*  msc    = (float*)(qproj + (size_t)NTOK * NH * 1024);
    float*  wmem   = msc + (size_t)NTOK * NH * NM;
    ushort* qkvb   = (ushort*)(wmem + (size_t)NTOK * NH * 16);
    ushort* Wqkvb  = qkvb + (size_t)3 * OUTT;
    ushort* Woutb  = Wqkvb + (size_t)3072 * 1024;
    ushort* xb     = Woutb + (size_t)1024 * 1024;
    ushort* mergedb = xb;                                   // alias: xb dead after qkv gemm

    const int na4 = NTOK * DIM / 4, nb4 = 3 * DIM * DIM / 4, nc4 = DIM * DIM / 4;

    // 1. bf16 conversions
    cvt3_kernel<<<(na4 + nb4 + nc4 + 255) / 256, 256, 0, stream>>>(
        x, xb, na4, Wqkv, Wqkvb, nb4, Wout, Woutb, nc4);
    // 2+3. FUSED: qkv GEMM (384 blocks) + layernorm of mem rows (6144 blocks).
    //      ln is memory-wall-bound (2.1 TB/s regardless of structure, R2-R4);
    //      overlapping it with the MFMA-bound GEMM hides most of its 47us.
    qkv_ln_fused_kernel<<<QKV_BLKS + MEMROWS / 4, 256, 0, stream>>>(
        xb, Wqkvb, bqkv, out, qkvb, pq, pk, pv, mem_n);
    // 4. qproj (MFMA, per head)
    mfma_qproj_kernel<<<dim3(8, 16, NH), 256, 0, stream>>>(
        qkvb, Wqkvb + (size_t)DIM * DIM, qproj);
    // 5. mem scores (fused MFMA per token)
    msc_fused_kernel<<<NTOK / 4, 256, 0, stream>>>(qproj, mem_n, qkvb, bqkv, msc);
    // 6. flash attention (8-wave split-KV) -> mergedb bf16, wmem
    flash_attn_kernel<<<dim3(16, 32), 512, 0, stream>>>(qkvb, msc, mergedb, wmem);
    // 7. wvec
    wvec_kernel<<<NTOK, 256, 0, stream>>>(wmem, mem_n, wvecb);
    // 8. vproj (MFMA, per head): mergedb += wvec@Wv^T + wsum*bv (in place)
    mfma_vproj_kernel<<<dim3(16, NH), 256, 0, stream>>>(
        wvecb, Wqkvb + (size_t)2 * DIM * DIM, bqkv + 2 * DIM, wmem, mergedb);
    // 9. out GEMM (MFMA) -> d_out fp32
    mfma_out_kernel<<<dim3(8, 16), 256, 0, stream>>>(mergedb, Woutb, bout, out);
}